// Round 6
// baseline (3787.254 us; speedup 1.0000x reference)
//
#include <hip/hip_runtime.h>

typedef _Float16 f16x2 __attribute__((ext_vector_type(2)));

#define NB 256   // batch
#define NT 512   // time
#define NI 64    // input
#define NH 256   // hidden
#define SPB 2    // sequences per block
#define NBLK (NB / SPB)   // 128 blocks

// w_hh packed: flat f16x2 index n = (((g*2+half)*16 + q)*256 + j)*4 + e
//   value = f16 pair of w_hh[(g*256+j)*256 + half*128 + 8q + 2e + {0,1}]
// -> one coalesced float4 (dwordx4) load per (gate,q) per lane (j,half).
#define WHH_N (6*16*256*4)   // 98304 f16x2 = 384 KB
// w_ih packed (verified round-2 layout): [(g*8+cq)][j][cc] f16x2
#define WIH_N (3*8*256*4)    // 24576 f16x2 = 96 KB

// ---------------- weight prep: fp32 -> f16x2 packed layouts ----------------
__global__ __launch_bounds__(256) void gru_prep_kernel(
    const float* __restrict__ w_ih, const float* __restrict__ w_hh,
    f16x2* __restrict__ whh_p, f16x2* __restrict__ wih_p)
{
  int n = blockIdx.x * 256 + threadIdx.x;
  if (n < WHH_N) {
    int e = n & 3, j = (n >> 2) & 255, q = (n >> 10) & 15, slab = n >> 14; // 0..5
    int g = slab >> 1, half = slab & 1;
    const float* src = w_hh + (g * 256 + j) * 256 + half * 128 + 8 * q + 2 * e;
    whh_p[n] = f16x2{(_Float16)src[0], (_Float16)src[1]};
  } else if (n < WHH_N + WIH_N) {
    int m = n - WHH_N;
    int cc = m & 3, j = (m >> 2) & 255, cq = (m >> 10) & 7, g = m >> 13;
    int c = cq * 4 + cc;
    const float* src = w_ih + (g * 256 + j) * 64 + 2 * c;
    wih_p[m] = f16x2{(_Float16)src[0], (_Float16)src[1]};
  }
}

__device__ __forceinline__ float sigm(float v) {
  return __builtin_amdgcn_rcpf(1.0f + __expf(-v));
}
__device__ __forceinline__ float tanh_f(float v) {
  return 1.0f - 2.0f * __builtin_amdgcn_rcpf(1.0f + __expf(2.0f * v));
}

// ---------------- persistent recurrent kernel: 1 block = 2 sequences ----------------
// 512 threads: thread (j = tid&255, half = tid>>8) computes the `half` 128-wide
// slice of the 3 gate dots for hidden unit j, for BOTH sequences.
// Weights are NOT register-resident (rounds 3-5 showed that miscompiles): they are
// streamed from L2 every step with coalesced float4 loads; 2 seqs amortize the stream.
__global__ __launch_bounds__(512, 2) void gru_kernel(
    const float* __restrict__ x,      // [B, T, I]
    const float* __restrict__ b_ih,   // [768]
    const float* __restrict__ b_hh,   // [768]
    const float* __restrict__ w_out,  // [256]
    const float* __restrict__ b_out,  // [1]
    const f16x2* __restrict__ whh_p,
    const f16x2* __restrict__ wih_p,
    float* __restrict__ out)          // [T, B]
{
  __shared__ __align__(16) f16x2 wih_lds[WIH_N];      // 96 KB
  __shared__ __align__(16) f16x2 h_lds[2][SPB][128];  // double-buffered h (f16), per seq
  __shared__ __align__(16) f16x2 x_lds[SPB][4][32];   // 4 timesteps of x (f16), per seq
  __shared__ float prA[SPB][256], prB[SPB][256], prC[SPB][256], prD[SPB][256];
  __shared__ float red[SPB][4];

  const int tid  = threadIdx.x;
  const int j    = tid & 255;
  const int half = tid >> 8;
  const int b0   = blockIdx.x * SPB;

  // stage w_ih into LDS (coalesced)
  for (int n = tid; n < WIH_N; n += 512) wih_lds[n] = wih_p[n];

  const float bih0 = b_ih[j], bih1 = b_ih[256 + j], bih2 = b_ih[512 + j];
  const float bhh0 = b_hh[j], bhh1 = b_hh[256 + j], bhh2 = b_hh[512 + j];
  const float wo = w_out[j];
  const float bo = b_out[0];

  float h[SPB] = {0.0f, 0.0f};
  ((_Float16*)h_lds[0])[tid] = (_Float16)0.0f;   // zero both seqs' h (512 f16 total)

  const float* xb0 = x + (size_t)(b0 + 0) * (NT * NI);
  const float* xb1 = x + (size_t)(b0 + 1) * (NT * NI);
  const float4* wq4 = (const float4*)whh_p;      // tuple ((g*2+half)*16+q)*256 + j
  __syncthreads();

  for (int tc = 0; tc < NT / 4; ++tc) {
    // ---- stage x (f16) for 4 timesteps x 2 seqs: one element per thread ----
    {
      const float* src = half ? xb1 : xb0;
      ((_Float16*)x_lds)[tid] = (_Float16)src[tc * 256 + j];
    }
    __syncthreads();

    // ---- gi partials for 4 steps x 2 seqs (w_ih from LDS; round-2 verified pattern) ----
    float gr[SPB][4], gz[SPB][4], gn[SPB][4];
    #pragma unroll
    for (int s = 0; s < SPB; ++s)
      #pragma unroll
      for (int k = 0; k < 4; ++k) { gr[s][k] = 0; gz[s][k] = 0; gn[s][k] = 0; }
    {
      const float4* wq = (const float4*)wih_lds;
      #pragma unroll
      for (int cqi = 0; cqi < 4; ++cqi) {
        const int cq = half * 4 + cqi;
        float4 A0 = wq[(0 * 8 + cq) * 256 + j];
        float4 A1 = wq[(1 * 8 + cq) * 256 + j];
        float4 A2 = wq[(2 * 8 + cq) * 256 + j];
        f16x2 a0[4] = {__builtin_bit_cast(f16x2, A0.x), __builtin_bit_cast(f16x2, A0.y),
                       __builtin_bit_cast(f16x2, A0.z), __builtin_bit_cast(f16x2, A0.w)};
        f16x2 a1[4] = {__builtin_bit_cast(f16x2, A1.x), __builtin_bit_cast(f16x2, A1.y),
                       __builtin_bit_cast(f16x2, A1.z), __builtin_bit_cast(f16x2, A1.w)};
        f16x2 a2[4] = {__builtin_bit_cast(f16x2, A2.x), __builtin_bit_cast(f16x2, A2.y),
                       __builtin_bit_cast(f16x2, A2.z), __builtin_bit_cast(f16x2, A2.w)};
        #pragma unroll
        for (int s = 0; s < SPB; ++s) {
          #pragma unroll
          for (int k = 0; k < 4; ++k) {
            float4 X = ((const float4*)x_lds[s][k])[cq];
            f16x2 xv[4] = {__builtin_bit_cast(f16x2, X.x), __builtin_bit_cast(f16x2, X.y),
                           __builtin_bit_cast(f16x2, X.z), __builtin_bit_cast(f16x2, X.w)};
            #pragma unroll
            for (int cc = 0; cc < 4; ++cc) {
              gr[s][k] = __builtin_amdgcn_fdot2(a0[cc], xv[cc], gr[s][k], false);
              gz[s][k] = __builtin_amdgcn_fdot2(a1[cc], xv[cc], gz[s][k], false);
              gn[s][k] = __builtin_amdgcn_fdot2(a2[cc], xv[cc], gn[s][k], false);
            }
          }
        }
      }
    }

    // ---- 4 recurrent steps ----
    #pragma unroll
    for (int k = 0; k < 4; ++k) {
      const int t = tc * 4 + k;
      const float4* hq0 = (const float4*)h_lds[k & 1][0] + half * 16;
      const float4* hq1 = (const float4*)h_lds[k & 1][1] + half * 16;
      float aR0[SPB] = {0, 0}, aR1[SPB] = {0, 0};
      float aZ0[SPB] = {0, 0}, aZ1[SPB] = {0, 0};
      float aN0[SPB] = {0, 0}, aN1[SPB] = {0, 0};

      #pragma unroll
      for (int q = 0; q < 16; ++q) {
        // weights streamed from L2 (same lines for all blocks -> L2-resident)
        float4 Wr = wq4[((0 * 2 + half) * 16 + q) * 256 + j];
        float4 Wz = wq4[((1 * 2 + half) * 16 + q) * 256 + j];
        float4 Wn = wq4[((2 * 2 + half) * 16 + q) * 256 + j];
        f16x2 wr[4] = {__builtin_bit_cast(f16x2, Wr.x), __builtin_bit_cast(f16x2, Wr.y),
                       __builtin_bit_cast(f16x2, Wr.z), __builtin_bit_cast(f16x2, Wr.w)};
        f16x2 wz[4] = {__builtin_bit_cast(f16x2, Wz.x), __builtin_bit_cast(f16x2, Wz.y),
                       __builtin_bit_cast(f16x2, Wz.z), __builtin_bit_cast(f16x2, Wz.w)};
        f16x2 wn[4] = {__builtin_bit_cast(f16x2, Wn.x), __builtin_bit_cast(f16x2, Wn.y),
                       __builtin_bit_cast(f16x2, Wn.z), __builtin_bit_cast(f16x2, Wn.w)};
        #pragma unroll
        for (int s = 0; s < SPB; ++s) {
          float4 hv = (s == 0) ? hq0[q] : hq1[q];   // broadcast ds_read_b128
          f16x2 e0 = __builtin_bit_cast(f16x2, hv.x);
          f16x2 e1 = __builtin_bit_cast(f16x2, hv.y);
          f16x2 e2 = __builtin_bit_cast(f16x2, hv.z);
          f16x2 e3 = __builtin_bit_cast(f16x2, hv.w);
          aR0[s] = __builtin_amdgcn_fdot2(wr[0], e0, aR0[s], false);
          aZ0[s] = __builtin_amdgcn_fdot2(wz[0], e0, aZ0[s], false);
          aN0[s] = __builtin_amdgcn_fdot2(wn[0], e0, aN0[s], false);
          aR1[s] = __builtin_amdgcn_fdot2(wr[1], e1, aR1[s], false);
          aZ1[s] = __builtin_amdgcn_fdot2(wz[1], e1, aZ1[s], false);
          aN1[s] = __builtin_amdgcn_fdot2(wn[1], e1, aN1[s], false);
          aR0[s] = __builtin_amdgcn_fdot2(wr[2], e2, aR0[s], false);
          aZ0[s] = __builtin_amdgcn_fdot2(wz[2], e2, aZ0[s], false);
          aN0[s] = __builtin_amdgcn_fdot2(wn[2], e2, aN0[s], false);
          aR1[s] = __builtin_amdgcn_fdot2(wr[3], e3, aR1[s], false);
          aZ1[s] = __builtin_amdgcn_fdot2(wz[3], e3, aZ1[s], false);
          aN1[s] = __builtin_amdgcn_fdot2(wn[3], e3, aN1[s], false);
        }
      }

      // half=1 publishes its partials; half=0 keeps its own in registers
      if (half) {
        #pragma unroll
        for (int s = 0; s < SPB; ++s) {
          prA[s][j] = aR0[s] + aR1[s] + gr[s][k];
          prB[s][j] = aZ0[s] + aZ1[s] + gz[s][k];
          prC[s][j] = aN0[s] + aN1[s];
          prD[s][j] = gn[s][k];
        }
      }
      __syncthreads();
      if (tid < 256) {  // == half 0: epilogue for both sequences
        float p[SPB];
        #pragma unroll
        for (int s = 0; s < SPB; ++s) {
          float rr = sigm(bih0 + bhh0 + aR0[s] + aR1[s] + gr[s][k] + prA[s][j]);
          float zz = sigm(bih1 + bhh1 + aZ0[s] + aZ1[s] + gz[s][k] + prB[s][j]);
          float nn = tanh_f(bih2 + gn[s][k] + prD[s][j] +
                            rr * (bhh2 + aN0[s] + aN1[s] + prC[s][j]));
          h[s] = (1.0f - zz) * nn + zz * h[s];
          ((_Float16*)h_lds[(k + 1) & 1][s])[j] = (_Float16)h[s];
          p[s] = h[s] * wo;
        }
        #pragma unroll
        for (int s = 0; s < SPB; ++s) {
          p[s] += __shfl_down(p[s], 32);
          p[s] += __shfl_down(p[s], 16);
          p[s] += __shfl_down(p[s], 8);
          p[s] += __shfl_down(p[s], 4);
          p[s] += __shfl_down(p[s], 2);
          p[s] += __shfl_down(p[s], 1);
        }
        if ((tid & 63) == 0) {
          red[0][tid >> 6] = p[0];
          red[1][tid >> 6] = p[1];
        }
      }
      __syncthreads();
      if (tid == 0) {
        out[t * NB + b0 + 0] = red[0][0] + red[0][1] + red[0][2] + red[0][3] + bo;
        out[t * NB + b0 + 1] = red[1][0] + red[1][1] + red[1][2] + red[1][3] + bo;
      }
    }
  }
}

extern "C" void kernel_launch(void* const* d_in, const int* in_sizes, int n_in,
                              void* d_out, int out_size, void* d_ws, size_t ws_size,
                              hipStream_t stream) {
  const float* x     = (const float*)d_in[0];
  const float* w_ih  = (const float*)d_in[1];
  const float* w_hh  = (const float*)d_in[2];
  const float* b_ih  = (const float*)d_in[3];
  const float* b_hh  = (const float*)d_in[4];
  const float* w_out = (const float*)d_in[5];
  const float* b_out = (const float*)d_in[6];
  float* out = (float*)d_out;

  f16x2* whh_p = (f16x2*)d_ws;       // 384 KB
  f16x2* wih_p = whh_p + WHH_N;      // 96 KB   (total 480 KB)

  gru_prep_kernel<<<480, 256, 0, stream>>>(w_ih, w_hh, whh_p, wih_p);
  gru_kernel<<<NBLK, 512, 0, stream>>>(x, b_ih, b_hh, w_out, b_out,
                                       whh_p, wih_p, out);
}

// Round 7
// 3412.082 us; speedup vs baseline: 1.1100x; 1.1100x over previous
//
#include <hip/hip_runtime.h>

typedef _Float16 f16x2 __attribute__((ext_vector_type(2)));

#define NB 256   // batch
#define NT 512   // time
#define NI 64    // input
#define NH 256   // hidden
#define SPB 2    // sequences per block
#define NBLK (NB / SPB)   // 128 blocks

// w_hh packed: flat f16x2 index n = (((g*2+half)*16 + q)*256 + j)*4 + e
//   value = f16 pair of w_hh[(g*256+j)*256 + half*128 + 8q + 2e + {0,1}]
#define WHH_N (6*16*256*4)   // 98304 f16x2 = 384 KB
// w_ih packed (verified layout): [(g*8+cq)][j][cc] f16x2
#define WIH_N (3*8*256*4)    // 24576 f16x2 = 96 KB

// ---------------- weight prep: fp32 -> f16x2 packed layouts (verified R6) ----------------
__global__ __launch_bounds__(256) void gru_prep_kernel(
    const float* __restrict__ w_ih, const float* __restrict__ w_hh,
    f16x2* __restrict__ whh_p, f16x2* __restrict__ wih_p)
{
  int n = blockIdx.x * 256 + threadIdx.x;
  if (n < WHH_N) {
    int e = n & 3, j = (n >> 2) & 255, q = (n >> 10) & 15, slab = n >> 14; // 0..5
    int g = slab >> 1, half = slab & 1;
    const float* src = w_hh + (g * 256 + j) * 256 + half * 128 + 8 * q + 2 * e;
    whh_p[n] = f16x2{(_Float16)src[0], (_Float16)src[1]};
  } else if (n < WHH_N + WIH_N) {
    int m = n - WHH_N;
    int cc = m & 3, j = (m >> 2) & 255, cq = (m >> 10) & 7, g = m >> 13;
    int c = cq * 4 + cc;
    const float* src = w_ih + (g * 256 + j) * 64 + 2 * c;
    wih_p[m] = f16x2{(_Float16)src[0], (_Float16)src[1]};
  }
}

__device__ __forceinline__ float sigm(float v) {
  return __builtin_amdgcn_rcpf(1.0f + __expf(-v));
}
__device__ __forceinline__ float tanh_f(float v) {
  return 1.0f - 2.0f * __builtin_amdgcn_rcpf(1.0f + __expf(2.0f * v));
}

#define FDOT(W, X, A) __builtin_amdgcn_fdot2(__builtin_bit_cast(f16x2, W), \
                                             __builtin_bit_cast(f16x2, X), A, false)
#define GR(s, k) gr##s##k
#define GZ(s, k) gz##s##k
#define GN(s, k) gn##s##k

// ---------------- persistent recurrent kernel: 1 block = 2 sequences ----------------
// Same algorithm as the passing R6 kernel, but with ZERO local arrays: every
// accumulator is a named scalar (R6's small indexed locals stayed as scratch
// allocas -> 1.2 GB spill traffic -> latency-bound at 13% VALUBusy).
__global__ __launch_bounds__(512, 2) void gru_kernel(
    const float* __restrict__ x,      // [B, T, I]
    const float* __restrict__ b_ih,   // [768]
    const float* __restrict__ b_hh,   // [768]
    const float* __restrict__ w_out,  // [256]
    const float* __restrict__ b_out,  // [1]
    const f16x2* __restrict__ whh_p,
    const f16x2* __restrict__ wih_p,
    float* __restrict__ out)          // [T, B]
{
  __shared__ __align__(16) f16x2 wih_lds[WIH_N];      // 96 KB
  __shared__ __align__(16) f16x2 h_lds[2][SPB][128];  // double-buffered h (f16), per seq
  __shared__ __align__(16) f16x2 x_lds[SPB][4][32];   // 4 timesteps of x (f16), per seq
  __shared__ float prA[SPB][256], prB[SPB][256], prC[SPB][256], prD[SPB][256];
  __shared__ float red[SPB][4];

  const int tid  = threadIdx.x;
  const int j    = tid & 255;
  const int half = tid >> 8;
  const int b0   = blockIdx.x * SPB;

  // stage w_ih into LDS (coalesced)
  for (int n = tid; n < WIH_N; n += 512) wih_lds[n] = wih_p[n];

  const float bih0 = b_ih[j], bih1 = b_ih[256 + j], bih2 = b_ih[512 + j];
  const float bhh0 = b_hh[j], bhh1 = b_hh[256 + j], bhh2 = b_hh[512 + j];
  const float wo = w_out[j];
  const float bo = b_out[0];

  float h_s0 = 0.0f, h_s1 = 0.0f;
  ((_Float16*)h_lds[0])[tid] = (_Float16)0.0f;   // zero both seqs' h

  const float* xb0 = x + (size_t)(b0 + 0) * (NT * NI);
  const float* xb1 = x + (size_t)(b0 + 1) * (NT * NI);
  const float4* wq4 = (const float4*)whh_p;      // tuple ((g*2+half)*16+q)*256 + j
  __syncthreads();

  for (int tc = 0; tc < NT / 4; ++tc) {
    // ---- stage x (f16) for 4 timesteps x 2 seqs: one element per thread ----
    {
      const float* src = half ? xb1 : xb0;
      ((_Float16*)x_lds)[tid] = (_Float16)src[tc * 256 + j];
    }
    __syncthreads();

    // ---- gi partials for 4 steps x 2 seqs — all named scalars ----
    float gr00 = 0, gz00 = 0, gn00 = 0, gr01 = 0, gz01 = 0, gn01 = 0;
    float gr02 = 0, gz02 = 0, gn02 = 0, gr03 = 0, gz03 = 0, gn03 = 0;
    float gr10 = 0, gz10 = 0, gn10 = 0, gr11 = 0, gz11 = 0, gn11 = 0;
    float gr12 = 0, gz12 = 0, gn12 = 0, gr13 = 0, gz13 = 0, gn13 = 0;
    {
      const float4* wq = (const float4*)wih_lds;
      #pragma unroll
      for (int cqi = 0; cqi < 4; ++cqi) {
        const int cq = half * 4 + cqi;
        float4 A0 = wq[(0 * 8 + cq) * 256 + j];
        float4 A1 = wq[(1 * 8 + cq) * 256 + j];
        float4 A2 = wq[(2 * 8 + cq) * 256 + j];
#define GI_SK(s, k) { \
        float4 X = ((const float4*)x_lds[s][k])[cq]; \
        GR(s, k) = FDOT(A0.x, X.x, GR(s, k)); \
        GR(s, k) = FDOT(A0.y, X.y, GR(s, k)); \
        GR(s, k) = FDOT(A0.z, X.z, GR(s, k)); \
        GR(s, k) = FDOT(A0.w, X.w, GR(s, k)); \
        GZ(s, k) = FDOT(A1.x, X.x, GZ(s, k)); \
        GZ(s, k) = FDOT(A1.y, X.y, GZ(s, k)); \
        GZ(s, k) = FDOT(A1.z, X.z, GZ(s, k)); \
        GZ(s, k) = FDOT(A1.w, X.w, GZ(s, k)); \
        GN(s, k) = FDOT(A2.x, X.x, GN(s, k)); \
        GN(s, k) = FDOT(A2.y, X.y, GN(s, k)); \
        GN(s, k) = FDOT(A2.z, X.z, GN(s, k)); \
        GN(s, k) = FDOT(A2.w, X.w, GN(s, k)); }
        GI_SK(0, 0) GI_SK(0, 1) GI_SK(0, 2) GI_SK(0, 3)
        GI_SK(1, 0) GI_SK(1, 1) GI_SK(1, 2) GI_SK(1, 3)
#undef GI_SK
      }
    }

    // ---- 4 recurrent steps (macro-unrolled, named scalars only) ----
#define STEP(k) { \
    const int t = tc * 4 + (k); \
    const float4* hq0 = (const float4*)h_lds[(k) & 1][0] + half * 16; \
    const float4* hq1 = (const float4*)h_lds[(k) & 1][1] + half * 16; \
    float R0 = 0, Z0 = 0, N0 = 0, R1 = 0, Z1 = 0, N1 = 0; \
    _Pragma("unroll") \
    for (int q = 0; q < 16; ++q) { \
      float4 Wr = wq4[((0 * 2 + half) * 16 + q) * 256 + j]; \
      float4 Wz = wq4[((1 * 2 + half) * 16 + q) * 256 + j]; \
      float4 Wn = wq4[((2 * 2 + half) * 16 + q) * 256 + j]; \
      float4 H0 = hq0[q]; \
      float4 H1 = hq1[q]; \
      R0 = FDOT(Wr.x, H0.x, R0); R0 = FDOT(Wr.y, H0.y, R0); \
      R0 = FDOT(Wr.z, H0.z, R0); R0 = FDOT(Wr.w, H0.w, R0); \
      Z0 = FDOT(Wz.x, H0.x, Z0); Z0 = FDOT(Wz.y, H0.y, Z0); \
      Z0 = FDOT(Wz.z, H0.z, Z0); Z0 = FDOT(Wz.w, H0.w, Z0); \
      N0 = FDOT(Wn.x, H0.x, N0); N0 = FDOT(Wn.y, H0.y, N0); \
      N0 = FDOT(Wn.z, H0.z, N0); N0 = FDOT(Wn.w, H0.w, N0); \
      R1 = FDOT(Wr.x, H1.x, R1); R1 = FDOT(Wr.y, H1.y, R1); \
      R1 = FDOT(Wr.z, H1.z, R1); R1 = FDOT(Wr.w, H1.w, R1); \
      Z1 = FDOT(Wz.x, H1.x, Z1); Z1 = FDOT(Wz.y, H1.y, Z1); \
      Z1 = FDOT(Wz.z, H1.z, Z1); Z1 = FDOT(Wz.w, H1.w, Z1); \
      N1 = FDOT(Wn.x, H1.x, N1); N1 = FDOT(Wn.y, H1.y, N1); \
      N1 = FDOT(Wn.z, H1.z, N1); N1 = FDOT(Wn.w, H1.w, N1); \
    } \
    if (half) { \
      prA[0][j] = R0 + GR(0, k); prB[0][j] = Z0 + GZ(0, k); \
      prC[0][j] = N0;            prD[0][j] = GN(0, k); \
      prA[1][j] = R1 + GR(1, k); prB[1][j] = Z1 + GZ(1, k); \
      prC[1][j] = N1;            prD[1][j] = GN(1, k); \
    } \
    __syncthreads(); \
    if (tid < 256) { \
      float rr0 = sigm(bih0 + bhh0 + R0 + GR(0, k) + prA[0][j]); \
      float zz0 = sigm(bih1 + bhh1 + Z0 + GZ(0, k) + prB[0][j]); \
      float nn0 = tanh_f(bih2 + GN(0, k) + prD[0][j] + rr0 * (bhh2 + N0 + prC[0][j])); \
      h_s0 = (1.0f - zz0) * nn0 + zz0 * h_s0; \
      float rr1 = sigm(bih0 + bhh0 + R1 + GR(1, k) + prA[1][j]); \
      float zz1 = sigm(bih1 + bhh1 + Z1 + GZ(1, k) + prB[1][j]); \
      float nn1 = tanh_f(bih2 + GN(1, k) + prD[1][j] + rr1 * (bhh2 + N1 + prC[1][j])); \
      h_s1 = (1.0f - zz1) * nn1 + zz1 * h_s1; \
      ((_Float16*)h_lds[((k) + 1) & 1][0])[j] = (_Float16)h_s0; \
      ((_Float16*)h_lds[((k) + 1) & 1][1])[j] = (_Float16)h_s1; \
      float p0 = h_s0 * wo, p1 = h_s1 * wo; \
      p0 += __shfl_down(p0, 32); p1 += __shfl_down(p1, 32); \
      p0 += __shfl_down(p0, 16); p1 += __shfl_down(p1, 16); \
      p0 += __shfl_down(p0, 8);  p1 += __shfl_down(p1, 8); \
      p0 += __shfl_down(p0, 4);  p1 += __shfl_down(p1, 4); \
      p0 += __shfl_down(p0, 2);  p1 += __shfl_down(p1, 2); \
      p0 += __shfl_down(p0, 1);  p1 += __shfl_down(p1, 1); \
      if ((tid & 63) == 0) { red[0][tid >> 6] = p0; red[1][tid >> 6] = p1; } \
    } \
    __syncthreads(); \
    if (tid == 0) { \
      out[t * NB + b0 + 0] = red[0][0] + red[0][1] + red[0][2] + red[0][3] + bo; \
      out[t * NB + b0 + 1] = red[1][0] + red[1][1] + red[1][2] + red[1][3] + bo; \
    } }

    STEP(0) STEP(1) STEP(2) STEP(3)
#undef STEP
  }
}

extern "C" void kernel_launch(void* const* d_in, const int* in_sizes, int n_in,
                              void* d_out, int out_size, void* d_ws, size_t ws_size,
                              hipStream_t stream) {
  const float* x     = (const float*)d_in[0];
  const float* w_ih  = (const float*)d_in[1];
  const float* w_hh  = (const float*)d_in[2];
  const float* b_ih  = (const float*)d_in[3];
  const float* b_hh  = (const float*)d_in[4];
  const float* w_out = (const float*)d_in[5];
  const float* b_out = (const float*)d_in[6];
  float* out = (float*)d_out;

  f16x2* whh_p = (f16x2*)d_ws;       // 384 KB
  f16x2* wih_p = whh_p + WHH_N;      // 96 KB   (total 480 KB)

  gru_prep_kernel<<<480, 256, 0, stream>>>(w_ih, w_hh, whh_p, wih_p);
  gru_kernel<<<NBLK, 512, 0, stream>>>(x, b_ih, b_hh, w_out, b_out,
                                       whh_p, wih_p, out);
}